// Round 7
// baseline (392.942 us; speedup 1.0000x reference)
//
#include <hip/hip_runtime.h>
#include <stdint.h>

typedef _Float16 h8v __attribute__((ext_vector_type(8)));
typedef float f4v __attribute__((ext_vector_type(4)));
typedef _Float16 f16;

#define NB 8
#define CC 128
#define CB 64
#define NN 4096

// load 8 consecutive fp32, convert to fp16 MFMA fragment (two 16B loads)
__device__ __forceinline__ h8v ld8f(const float* __restrict__ p){
    const f4v a = *(const f4v*)p;
    const f4v b = *(const f4v*)(p + 4);
    h8v r;
    r[0] = (f16)a[0]; r[1] = (f16)a[1]; r[2] = (f16)a[2]; r[3] = (f16)a[3];
    r[4] = (f16)b[0]; r[5] = (f16)b[1]; r[6] = (f16)b[2]; r[7] = (f16)b[3];
    return r;
}

// ---------------------------------------------------------------------------
// Kernel 1: projections (fp32 in -> fp16 intermediates).
// ---------------------------------------------------------------------------
__global__ __launch_bounds__(256) void proj_kernel(
    const float* __restrict__ x, const float* __restrict__ wth,
    const float* __restrict__ wph, const float* __restrict__ wg,
    f16* __restrict__ thetaT, f16* __restrict__ phiT, f16* __restrict__ gbuf)
{
    __shared__ __align__(16) f16 xT[64][136];
    const int b  = blockIdx.x & 7;          // XCD-swizzled (batch -> XCD)
    const int n0 = (blockIdx.x >> 3) << 6;
    const int t  = threadIdx.x;

    #pragma unroll
    for (int i = 0; i < 8; i++){
        int v  = t + 256 * i;
        int c  = v >> 4;
        int j0 = (v & 15) << 2;
        const f4v xv = *(const f4v*)&x[((size_t)(b * CC + c)) * NN + n0 + j0];
        #pragma unroll
        for (int jj = 0; jj < 4; jj++) xT[j0 + jj][c] = (f16)xv[jj];
    }
    __syncthreads();

    const int w = t >> 6, lane = t & 63, quad = lane >> 4, l15 = lane & 15;

    h8v a[4];
    #pragma unroll
    for (int kc = 0; kc < 4; kc++)
        a[kc] = *(const h8v*)&xT[w * 16 + l15][kc * 32 + quad * 8];

    #pragma unroll
    for (int m3 = 0; m3 < 2; m3++){
        const float* W = (m3 == 0) ? wth : wph;
        f16* OUT       = (m3 == 0) ? thetaT : phiT;
        for (int ks = 0; ks < 4; ks++){
            f4v acc = {0.f, 0.f, 0.f, 0.f};
            #pragma unroll
            for (int kc = 0; kc < 4; kc++){
                const h8v bf = ld8f(&W[(ks * 16 + l15) * CC + kc * 32 + quad * 8]);
                acc = __builtin_amdgcn_mfma_f32_16x16x32_f16(a[kc], bf, acc, 0, 0, 0);
            }
            #pragma unroll
            for (int r = 0; r < 4; r++){
                int nl = w * 16 + quad * 4 + r;
                int k  = ks * 16 + l15;
                OUT[((size_t)(b * NN + n0 + nl)) * CB + k] = (f16)acc[r];
            }
        }
    }

    h8v aw[4];
    #pragma unroll
    for (int kc = 0; kc < 4; kc++)
        aw[kc] = ld8f(&wg[(w * 16 + l15) * CC + kc * 32 + quad * 8]);
    for (int ns = 0; ns < 4; ns++){
        f4v acc = {0.f, 0.f, 0.f, 0.f};
        #pragma unroll
        for (int kc = 0; kc < 4; kc++){
            const h8v bx = *(const h8v*)&xT[ns * 16 + l15][kc * 32 + quad * 8];
            acc = __builtin_amdgcn_mfma_f32_16x16x32_f16(aw[kc], bx, acc, 0, 0, 0);
        }
        #pragma unroll
        for (int r = 0; r < 4; r++){
            int k = w * 16 + quad * 4 + r;
            int n = n0 + ns * 16 + l15;
            gbuf[((size_t)(b * CB + k)) * NN + n] = (f16)acc[r];
        }
    }
}

// ---------------------------------------------------------------------------
// Kernel 2: flash attention, key-split, 128-key chunks, XCD-swizzled.
// LDS overlay: P-tiles (loop phase) and merge buffers (epilogue phase) share
// the same storage -> 17.4 KB/block -> 8 blocks/CU = 32 waves/CU (2x R6 TLP).
// __launch_bounds__(256,8) pins VGPR <= 64 for 8 waves/SIMD.
// ---------------------------------------------------------------------------
union AttnShared {
    f16 plds[4][16 * 136];                 // 17408 B — loop phase (per-wave P tile)
    struct {                               // 16896 B — epilogue phase
        float oL[4][16][64];
        float mwS[4][16];
        float lwS[4][16];
    } m;
};

__global__ __launch_bounds__(256, 8) void attn_kernel(
    const f16* __restrict__ thetaT, const f16* __restrict__ phiT,
    const f16* __restrict__ gbuf, f16* __restrict__ yT)
{
    __shared__ __align__(16) AttnShared sh;

    const int b  = blockIdx.x & 7;                   // XCD-swizzled
    const int n0 = (blockIdx.x >> 3) << 4;           // 256 q-tiles per batch
    const int t  = threadIdx.x;
    const int w = t >> 6, lane = t & 63, quad = lane >> 4, l15 = lane & 15;

    // A-frags (theta^T rows) — same 16 queries for all 4 waves
    const size_t trow = ((size_t)(b * NN + n0 + l15)) * CB;
    const h8v a0 = *(const h8v*)&thetaT[trow + quad * 8];
    const h8v a1 = *(const h8v*)&thetaT[trow + 32 + quad * 8];

    float mrun[4], lrun[4];
    f4v o[4];
    const f4v zf = {0.f, 0.f, 0.f, 0.f};
    #pragma unroll
    for (int r = 0; r < 4; r++){ mrun[r] = -1e30f; lrun[r] = 0.f; }
    #pragma unroll
    for (int tt = 0; tt < 4; tt++) o[tt] = zf;

    const int kbase = w << 10;           // this wave's 1024-key slice
    const f16* phiP = phiT + ((size_t)(b * NN + kbase + l15)) * CB + quad * 8;
    const f16* gP   = gbuf + ((size_t)(b * CB + l15)) * NN + kbase + quad * 8;
    f16* const pw   = &sh.plds[w][0];

    for (int kb = 0; kb < 8; kb++){
        // ---- S = theta^T phi for 128 keys (8 sub-tiles of 16) ----
        f4v s[8];
        #pragma unroll
        for (int tt = 0; tt < 8; tt++){
            const f16* pr = phiP + (size_t)(tt * 16) * CB;
            const h8v pb0 = *(const h8v*)pr;
            const h8v pb1 = *(const h8v*)(pr + 32);
            f4v sv = zf;
            sv = __builtin_amdgcn_mfma_f32_16x16x32_f16(a0, pb0, sv, 0, 0, 0);
            sv = __builtin_amdgcn_mfma_f32_16x16x32_f16(a1, pb1, sv, 0, 0, 0);
            s[tt] = sv;
        }
        // ---- online softmax over 128 keys ----
        float rmax[4];
        #pragma unroll
        for (int r = 0; r < 4; r++){
            float m01 = fmaxf(s[0][r], s[1][r]), m23 = fmaxf(s[2][r], s[3][r]);
            float m45 = fmaxf(s[4][r], s[5][r]), m67 = fmaxf(s[6][r], s[7][r]);
            rmax[r] = fmaxf(fmaxf(m01, m23), fmaxf(m45, m67));
        }
        #pragma unroll
        for (int mask = 1; mask <= 8; mask <<= 1){
            #pragma unroll
            for (int r = 0; r < 4; r++)
                rmax[r] = fmaxf(rmax[r], __shfl_xor(rmax[r], mask));
        }
        float alpha[4];
        #pragma unroll
        for (int r = 0; r < 4; r++){
            float mn = fmaxf(mrun[r], rmax[r]);
            alpha[r] = __expf(mrun[r] - mn);
            mrun[r]  = mn;
            lrun[r] *= alpha[r];
        }
        #pragma unroll
        for (int tt = 0; tt < 8; tt++){
            #pragma unroll
            for (int r = 0; r < 4; r++){
                float p = __expf(s[tt][r] - mrun[r]);
                lrun[r] += p;
                pw[(quad * 4 + r) * 136 + tt * 16 + l15] = (f16)p;
            }
        }
        #pragma unroll
        for (int tt = 0; tt < 4; tt++)
            #pragma unroll
            for (int r = 0; r < 4; r++)
                o[tt][r] *= alpha[r];

        // ---- reload P as A-operand fragments (wave-private LDS) ----
        h8v pa[4];
        #pragma unroll
        for (int kc = 0; kc < 4; kc++)
            pa[kc] = *(const h8v*)&pw[l15 * 136 + kc * 32 + quad * 8];

        // ---- O += P * g^T over 128 keys (4 K-chunks of 32) ----
        #pragma unroll
        for (int tt = 0; tt < 4; tt++){
            const f16* gr = gP + (size_t)(tt * 16) * NN;
            #pragma unroll
            for (int kc = 0; kc < 4; kc++){
                const h8v gb = *(const h8v*)(gr + kc * 32);
                o[tt] = __builtin_amdgcn_mfma_f32_16x16x32_f16(pa[kc], gb, o[tt], 0, 0, 0);
            }
        }
        phiP += (size_t)128 * CB;
        gP   += 128;
    }

    // reduce denominator across the quad's 16 lanes (per-wave partial)
    #pragma unroll
    for (int mask = 1; mask <= 8; mask <<= 1){
        #pragma unroll
        for (int r = 0; r < 4; r++)
            lrun[r] += __shfl_xor(lrun[r], mask);
    }

    // phase switch: plds -> merge buffers (overlaid storage)
    __syncthreads();

    // publish per-wave partial state
    #pragma unroll
    for (int tt = 0; tt < 4; tt++)
        #pragma unroll
        for (int r = 0; r < 4; r++)
            sh.m.oL[w][quad * 4 + r][tt * 16 + l15] = o[tt][r];
    if (l15 == 0){
        #pragma unroll
        for (int r = 0; r < 4; r++){
            sh.m.mwS[w][quad * 4 + r] = mrun[r];
            sh.m.lwS[w][quad * 4 + r] = lrun[r];
        }
    }
    __syncthreads();

    // merge 4 partials: thread t -> col = t&63, rows (t>>6)*4 .. +3
    const int col = t & 63;
    #pragma unroll
    for (int rr = 0; rr < 4; rr++){
        const int row = (t >> 6) * 4 + rr;
        const float m0v = sh.m.mwS[0][row], m1v = sh.m.mwS[1][row];
        const float m2v = sh.m.mwS[2][row], m3v = sh.m.mwS[3][row];
        const float M = fmaxf(fmaxf(m0v, m1v), fmaxf(m2v, m3v));
        const float e0 = __expf(m0v - M), e1 = __expf(m1v - M);
        const float e2 = __expf(m2v - M), e3 = __expf(m3v - M);
        const float L = sh.m.lwS[0][row] * e0 + sh.m.lwS[1][row] * e1
                      + sh.m.lwS[2][row] * e2 + sh.m.lwS[3][row] * e3;
        const float val = sh.m.oL[0][row][col] * e0 + sh.m.oL[1][row][col] * e1
                        + sh.m.oL[2][row][col] * e2 + sh.m.oL[3][row][col] * e3;
        yT[((size_t)(b * NN + n0 + row)) * CB + col] = (f16)(val / L);
    }
}

// ---------------------------------------------------------------------------
// Kernel 3: out = w_last * y + x (fp32 out, fp32 residual).
// ---------------------------------------------------------------------------
__global__ __launch_bounds__(256) void out_kernel(
    const float* __restrict__ wl, const f16* __restrict__ yT,
    const float* __restrict__ x, float* __restrict__ out)
{
    const int b  = blockIdx.x & 7;          // XCD-swizzled
    const int n0 = (blockIdx.x >> 3) << 6;
    const int t  = threadIdx.x;
    const int w = t >> 6, lane = t & 63, quad = lane >> 4, l15 = lane & 15;

    h8v wlf[2][2];
    #pragma unroll
    for (int cs = 0; cs < 2; cs++)
        #pragma unroll
        for (int kc = 0; kc < 2; kc++)
            wlf[cs][kc] = ld8f(&wl[((w * 2 + cs) * 16 + l15) * CB + kc * 32 + quad * 8]);

    #pragma unroll
    for (int ns = 0; ns < 4; ns++){
        const size_t yrow = ((size_t)(b * NN + n0 + ns * 16 + l15)) * CB;
        const h8v yb0 = *(const h8v*)&yT[yrow + quad * 8];
        const h8v yb1 = *(const h8v*)&yT[yrow + 32 + quad * 8];
        #pragma unroll
        for (int cs = 0; cs < 2; cs++){
            f4v acc = {0.f, 0.f, 0.f, 0.f};
            acc = __builtin_amdgcn_mfma_f32_16x16x32_f16(wlf[cs][0], yb0, acc, 0, 0, 0);
            acc = __builtin_amdgcn_mfma_f32_16x16x32_f16(wlf[cs][1], yb1, acc, 0, 0, 0);
            #pragma unroll
            for (int r = 0; r < 4; r++){
                int c = (w * 2 + cs) * 16 + quad * 4 + r;
                size_t idx = ((size_t)(b * CC + c)) * NN + n0 + ns * 16 + l15;
                out[idx] = acc[r] + x[idx];
            }
        }
    }
}

extern "C" void kernel_launch(void* const* d_in, const int* in_sizes, int n_in,
                              void* d_out, int out_size, void* d_ws, size_t ws_size,
                              hipStream_t stream)
{
    const float* x   = (const float*)d_in[0];
    const float* wth = (const float*)d_in[1];
    const float* wph = (const float*)d_in[2];
    const float* wg  = (const float*)d_in[3];
    const float* wl  = (const float*)d_in[4];
    float* out = (float*)d_out;

    f16* thetaT = (f16*)d_ws;
    f16* phiT   = thetaT + (size_t)NB * NN * CB;
    f16* gbuf   = phiT   + (size_t)NB * NN * CB;
    f16* yT     = gbuf   + (size_t)NB * NN * CB;

    proj_kernel<<<NB * 64, 256, 0, stream>>>(x, wth, wph, wg, thetaT, phiT, gbuf);
    attn_kernel<<<NB * 256, 256, 0, stream>>>(thetaT, phiT, gbuf, yT);
    out_kernel <<<NB * 64, 256, 0, stream>>>(wl, yT, x, out);
}

// Round 8
// 204.264 us; speedup vs baseline: 1.9237x; 1.9237x over previous
//
#include <hip/hip_runtime.h>
#include <stdint.h>

typedef _Float16 h8v __attribute__((ext_vector_type(8)));
typedef float f4v __attribute__((ext_vector_type(4)));
typedef _Float16 f16;

#define NB 8
#define CC 128
#define CB 64
#define NN 4096

// load 8 consecutive fp32, convert to fp16 MFMA fragment (two 16B loads)
__device__ __forceinline__ h8v ld8f(const float* __restrict__ p){
    const f4v a = *(const f4v*)p;
    const f4v b = *(const f4v*)(p + 4);
    h8v r;
    r[0] = (f16)a[0]; r[1] = (f16)a[1]; r[2] = (f16)a[2]; r[3] = (f16)a[3];
    r[4] = (f16)b[0]; r[5] = (f16)b[1]; r[6] = (f16)b[2]; r[7] = (f16)b[3];
    return r;
}

// ---------------------------------------------------------------------------
// Kernel 1: projections (fp32 in -> fp16 intermediates).
// ---------------------------------------------------------------------------
__global__ __launch_bounds__(256) void proj_kernel(
    const float* __restrict__ x, const float* __restrict__ wth,
    const float* __restrict__ wph, const float* __restrict__ wg,
    f16* __restrict__ thetaT, f16* __restrict__ phiT, f16* __restrict__ gbuf)
{
    __shared__ __align__(16) f16 xT[64][136];
    const int b  = blockIdx.x & 7;          // XCD-swizzled (batch -> XCD)
    const int n0 = (blockIdx.x >> 3) << 6;
    const int t  = threadIdx.x;

    #pragma unroll
    for (int i = 0; i < 8; i++){
        int v  = t + 256 * i;
        int c  = v >> 4;
        int j0 = (v & 15) << 2;
        const f4v xv = *(const f4v*)&x[((size_t)(b * CC + c)) * NN + n0 + j0];
        #pragma unroll
        for (int jj = 0; jj < 4; jj++) xT[j0 + jj][c] = (f16)xv[jj];
    }
    __syncthreads();

    const int w = t >> 6, lane = t & 63, quad = lane >> 4, l15 = lane & 15;

    h8v a[4];
    #pragma unroll
    for (int kc = 0; kc < 4; kc++)
        a[kc] = *(const h8v*)&xT[w * 16 + l15][kc * 32 + quad * 8];

    #pragma unroll
    for (int m3 = 0; m3 < 2; m3++){
        const float* W = (m3 == 0) ? wth : wph;
        f16* OUT       = (m3 == 0) ? thetaT : phiT;
        for (int ks = 0; ks < 4; ks++){
            f4v acc = {0.f, 0.f, 0.f, 0.f};
            #pragma unroll
            for (int kc = 0; kc < 4; kc++){
                const h8v bf = ld8f(&W[(ks * 16 + l15) * CC + kc * 32 + quad * 8]);
                acc = __builtin_amdgcn_mfma_f32_16x16x32_f16(a[kc], bf, acc, 0, 0, 0);
            }
            #pragma unroll
            for (int r = 0; r < 4; r++){
                int nl = w * 16 + quad * 4 + r;
                int k  = ks * 16 + l15;
                OUT[((size_t)(b * NN + n0 + nl)) * CB + k] = (f16)acc[r];
            }
        }
    }

    h8v aw[4];
    #pragma unroll
    for (int kc = 0; kc < 4; kc++)
        aw[kc] = ld8f(&wg[(w * 16 + l15) * CC + kc * 32 + quad * 8]);
    for (int ns = 0; ns < 4; ns++){
        f4v acc = {0.f, 0.f, 0.f, 0.f};
        #pragma unroll
        for (int kc = 0; kc < 4; kc++){
            const h8v bx = *(const h8v*)&xT[ns * 16 + l15][kc * 32 + quad * 8];
            acc = __builtin_amdgcn_mfma_f32_16x16x32_f16(aw[kc], bx, acc, 0, 0, 0);
        }
        #pragma unroll
        for (int r = 0; r < 4; r++){
            int k = w * 16 + quad * 4 + r;
            int n = n0 + ns * 16 + l15;
            gbuf[((size_t)(b * CB + k)) * NN + n] = (f16)acc[r];
        }
    }
}

// ---------------------------------------------------------------------------
// Kernel 2: flash attention, query-parallel, cooperative LDS staging.
// Block = 64 queries (4 waves x 16q). Each 64-key chunk of phi & g is staged
// into LDS ONCE per block (coalesced dwordx4, double-buffered), then all 4
// waves read MFMA fragments from LDS. Cuts global VMEM instructions 4x vs
// the per-wave-gather versions (R3-R6) and moves scattered g gathers to the
// LDS pipe. +72-stride padding keeps LDS reads at free 2-way conflicts.
// ---------------------------------------------------------------------------
__global__ __launch_bounds__(256) void attn_kernel(
    const f16* __restrict__ thetaT, const f16* __restrict__ phiT,
    const f16* __restrict__ gbuf, f16* __restrict__ yT)
{
    __shared__ __align__(16) f16 phL[2][64 * 72];   // phi chunk  [key][dim]
    __shared__ __align__(16) f16 gL [2][64 * 72];   // g   chunk  [kdim][key]
    __shared__ __align__(16) f16 plds[4][16 * 72];  // per-wave P tile

    const int b  = blockIdx.x & 7;                  // XCD-swizzled
    const int q0 = (blockIdx.x >> 3) << 6;          // 64 q-tiles per batch
    const int t  = threadIdx.x;
    const int w = t >> 6, lane = t & 63, quad = lane >> 4, l15 = lane & 15;
    const int n0 = q0 + w * 16;

    // A-frags (theta^T rows) — wave w owns queries n0..n0+15
    const size_t trow = ((size_t)(b * NN + n0 + l15)) * CB;
    const h8v a0 = *(const h8v*)&thetaT[trow + quad * 8];
    const h8v a1 = *(const h8v*)&thetaT[trow + 32 + quad * 8];

    // staging mapping: 512 16B-segs per tile; thread t owns segs t and t+256.
    // seg s: row = s>>3 (0..63), col halves = (s&7)*8.
    const int r0 = t >> 3, r1 = r0 + 32, c = (t & 7) * 8;
    const f16* pphi0 = phiT + ((size_t)(b * NN + r0)) * CB + c;
    const f16* pphi1 = phiT + ((size_t)(b * NN + r1)) * CB + c;
    const f16* pg0   = gbuf + ((size_t)(b * CB + r0)) * NN + c;
    const f16* pg1   = gbuf + ((size_t)(b * CB + r1)) * NN + c;
    const int lA = r0 * 72 + c, lB = r1 * 72 + c;

    // prefetch + write chunk 0 into buf 0
    h8v nA = *(const h8v*)pphi0;
    h8v nB = *(const h8v*)pphi1;
    h8v nC = *(const h8v*)pg0;
    h8v nD = *(const h8v*)pg1;
    *(h8v*)&phL[0][lA] = nA;  *(h8v*)&phL[0][lB] = nB;
    *(h8v*)&gL [0][lA] = nC;  *(h8v*)&gL [0][lB] = nD;

    float mrun[4], lrun[4];
    f4v o[4];
    const f4v zf = {0.f, 0.f, 0.f, 0.f};
    #pragma unroll
    for (int r = 0; r < 4; r++){ mrun[r] = -1e30f; lrun[r] = 0.f; }
    #pragma unroll
    for (int tt = 0; tt < 4; tt++) o[tt] = zf;

    f16* const pw = &plds[w][0];

    for (int kb = 0; kb < 64; kb++){
        const int pb = kb & 1;
        __syncthreads();                      // buf pb fully written
        // prefetch next chunk into registers (overlaps with compute below)
        if (kb < 63){
            pphi0 += (size_t)64 * CB;  pphi1 += (size_t)64 * CB;
            pg0 += 64;                 pg1 += 64;
            nA = *(const h8v*)pphi0;   nB = *(const h8v*)pphi1;
            nC = *(const h8v*)pg0;     nD = *(const h8v*)pg1;
        }

        // ---- S = theta^T phi for 64 keys (4 sub-tiles of 16) ----
        f4v s[4];
        #pragma unroll
        for (int tt = 0; tt < 4; tt++){
            const f16* pr = &phL[pb][(tt * 16 + l15) * 72];
            const h8v pb0 = *(const h8v*)(pr + quad * 8);
            const h8v pb1 = *(const h8v*)(pr + 32 + quad * 8);
            f4v sv = zf;
            sv = __builtin_amdgcn_mfma_f32_16x16x32_f16(a0, pb0, sv, 0, 0, 0);
            sv = __builtin_amdgcn_mfma_f32_16x16x32_f16(a1, pb1, sv, 0, 0, 0);
            s[tt] = sv;
        }
        // ---- online softmax over 64 keys ----
        float rmax[4];
        #pragma unroll
        for (int r = 0; r < 4; r++)
            rmax[r] = fmaxf(fmaxf(s[0][r], s[1][r]), fmaxf(s[2][r], s[3][r]));
        #pragma unroll
        for (int mask = 1; mask <= 8; mask <<= 1){
            #pragma unroll
            for (int r = 0; r < 4; r++)
                rmax[r] = fmaxf(rmax[r], __shfl_xor(rmax[r], mask));
        }
        float alpha[4];
        #pragma unroll
        for (int r = 0; r < 4; r++){
            float mn = fmaxf(mrun[r], rmax[r]);
            alpha[r] = __expf(mrun[r] - mn);
            mrun[r]  = mn;
            lrun[r] *= alpha[r];
        }
        #pragma unroll
        for (int tt = 0; tt < 4; tt++){
            #pragma unroll
            for (int r = 0; r < 4; r++){
                float p = __expf(s[tt][r] - mrun[r]);
                lrun[r] += p;
                pw[(quad * 4 + r) * 72 + tt * 16 + l15] = (f16)p;
            }
        }
        #pragma unroll
        for (int tt = 0; tt < 4; tt++)
            #pragma unroll
            for (int r = 0; r < 4; r++)
                o[tt][r] *= alpha[r];

        // ---- reload P as A-operand fragments (wave-private LDS) ----
        const h8v pa0 = *(const h8v*)&pw[l15 * 72 + quad * 8];
        const h8v pa1 = *(const h8v*)&pw[l15 * 72 + 32 + quad * 8];

        // ---- O += P * g^T from LDS ----
        #pragma unroll
        for (int tt = 0; tt < 4; tt++){
            const f16* gr = &gL[pb][(tt * 16 + l15) * 72];
            const h8v gb0 = *(const h8v*)(gr + quad * 8);
            const h8v gb1 = *(const h8v*)(gr + 32 + quad * 8);
            o[tt] = __builtin_amdgcn_mfma_f32_16x16x32_f16(pa0, gb0, o[tt], 0, 0, 0);
            o[tt] = __builtin_amdgcn_mfma_f32_16x16x32_f16(pa1, gb1, o[tt], 0, 0, 0);
        }

        // ---- write next chunk into the other buffer ----
        if (kb < 63){
            const int nb = pb ^ 1;
            *(h8v*)&phL[nb][lA] = nA;  *(h8v*)&phL[nb][lB] = nB;
            *(h8v*)&gL [nb][lA] = nC;  *(h8v*)&gL [nb][lB] = nD;
        }
    }

    // final softmax denominator across the quad's 16 lanes
    #pragma unroll
    for (int mask = 1; mask <= 8; mask <<= 1){
        #pragma unroll
        for (int r = 0; r < 4; r++)
            lrun[r] += __shfl_xor(lrun[r], mask);
    }
    float inv[4];
    #pragma unroll
    for (int r = 0; r < 4; r++) inv[r] = 1.0f / lrun[r];
    #pragma unroll
    for (int tt = 0; tt < 4; tt++){
        #pragma unroll
        for (int r = 0; r < 4; r++){
            int q = quad * 4 + r;
            yT[((size_t)(b * NN + n0 + q)) * CB + tt * 16 + l15] = (f16)(o[tt][r] * inv[r]);
        }
    }
}

// ---------------------------------------------------------------------------
// Kernel 3: out = w_last * y + x (fp32 out, fp32 residual).
// ---------------------------------------------------------------------------
__global__ __launch_bounds__(256) void out_kernel(
    const float* __restrict__ wl, const f16* __restrict__ yT,
    const float* __restrict__ x, float* __restrict__ out)
{
    const int b  = blockIdx.x & 7;          // XCD-swizzled
    const int n0 = (blockIdx.x >> 3) << 6;
    const int t  = threadIdx.x;
    const int w = t >> 6, lane = t & 63, quad = lane >> 4, l15 = lane & 15;

    h8v wlf[2][2];
    #pragma unroll
    for (int cs = 0; cs < 2; cs++)
        #pragma unroll
        for (int kc = 0; kc < 2; kc++)
            wlf[cs][kc] = ld8f(&wl[((w * 2 + cs) * 16 + l15) * CB + kc * 32 + quad * 8]);

    #pragma unroll
    for (int ns = 0; ns < 4; ns++){
        const size_t yrow = ((size_t)(b * NN + n0 + ns * 16 + l15)) * CB;
        const h8v yb0 = *(const h8v*)&yT[yrow + quad * 8];
        const h8v yb1 = *(const h8v*)&yT[yrow + 32 + quad * 8];
        #pragma unroll
        for (int cs = 0; cs < 2; cs++){
            f4v acc = {0.f, 0.f, 0.f, 0.f};
            acc = __builtin_amdgcn_mfma_f32_16x16x32_f16(wlf[cs][0], yb0, acc, 0, 0, 0);
            acc = __builtin_amdgcn_mfma_f32_16x16x32_f16(wlf[cs][1], yb1, acc, 0, 0, 0);
            #pragma unroll
            for (int r = 0; r < 4; r++){
                int c = (w * 2 + cs) * 16 + quad * 4 + r;
                size_t idx = ((size_t)(b * CC + c)) * NN + n0 + ns * 16 + l15;
                out[idx] = acc[r] + x[idx];
            }
        }
    }
}

extern "C" void kernel_launch(void* const* d_in, const int* in_sizes, int n_in,
                              void* d_out, int out_size, void* d_ws, size_t ws_size,
                              hipStream_t stream)
{
    const float* x   = (const float*)d_in[0];
    const float* wth = (const float*)d_in[1];
    const float* wph = (const float*)d_in[2];
    const float* wg  = (const float*)d_in[3];
    const float* wl  = (const float*)d_in[4];
    float* out = (float*)d_out;

    f16* thetaT = (f16*)d_ws;
    f16* phiT   = thetaT + (size_t)NB * NN * CB;
    f16* gbuf   = phiT   + (size_t)NB * NN * CB;
    f16* yT     = gbuf   + (size_t)NB * NN * CB;

    proj_kernel<<<NB * 64, 256, 0, stream>>>(x, wth, wph, wg, thetaT, phiT, gbuf);
    attn_kernel<<<NB * 64, 256, 0, stream>>>(thetaT, phiT, gbuf, yT);
    out_kernel <<<NB * 64, 256, 0, stream>>>(wl, yT, x, out);
}

// Round 9
// 184.890 us; speedup vs baseline: 2.1253x; 1.1048x over previous
//
#include <hip/hip_runtime.h>
#include <stdint.h>

typedef _Float16 h8v __attribute__((ext_vector_type(8)));
typedef _Float16 h4v __attribute__((ext_vector_type(4)));
typedef float f4v __attribute__((ext_vector_type(4)));
typedef _Float16 f16;

#define NB 8
#define CC 128
#define CB 64
#define NN 4096

// load 8 consecutive fp32, convert to fp16 MFMA fragment (two 16B loads)
__device__ __forceinline__ h8v ld8f(const float* __restrict__ p){
    const f4v a = *(const f4v*)p;
    const f4v b = *(const f4v*)(p + 4);
    h8v r;
    r[0] = (f16)a[0]; r[1] = (f16)a[1]; r[2] = (f16)a[2]; r[3] = (f16)a[3];
    r[4] = (f16)b[0]; r[5] = (f16)b[1]; r[6] = (f16)b[2]; r[7] = (f16)b[3];
    return r;
}

// ---------------------------------------------------------------------------
// Kernel 1: projections (fp32 in -> fp16 intermediates).
// Operand order chosen per output so C/D rows = contiguous dim -> packed
// b64 global stores (12/thread) instead of 48 scalar f16 stores.
// ---------------------------------------------------------------------------
__global__ __launch_bounds__(256) void proj_kernel(
    const float* __restrict__ x, const float* __restrict__ wth,
    const float* __restrict__ wph, const float* __restrict__ wg,
    f16* __restrict__ thetaT, f16* __restrict__ phiT, f16* __restrict__ gbuf)
{
    __shared__ __align__(16) f16 xT[64][136];
    const int b  = blockIdx.x & 7;          // XCD-swizzled (batch -> XCD)
    const int n0 = (blockIdx.x >> 3) << 6;
    const int t  = threadIdx.x;

    #pragma unroll
    for (int i = 0; i < 8; i++){
        int v  = t + 256 * i;
        int c  = v >> 4;
        int j0 = (v & 15) << 2;
        const f4v xv = *(const f4v*)&x[((size_t)(b * CC + c)) * NN + n0 + j0];
        #pragma unroll
        for (int jj = 0; jj < 4; jj++) xT[j0 + jj][c] = (f16)xv[jj];
    }
    __syncthreads();

    const int w = t >> 6, lane = t & 63, quad = lane >> 4, l15 = lane & 15;

    // B-frags from xT (n = w*16 + l15) for theta/phi
    h8v bx[4];
    #pragma unroll
    for (int kc = 0; kc < 4; kc++)
        bx[kc] = *(const h8v*)&xT[w * 16 + l15][kc * 32 + quad * 8];

    // theta & phi: A = W rows (k as M) -> D[row=k][col=n]; pack 4 k per store
    #pragma unroll
    for (int m3 = 0; m3 < 2; m3++){
        const float* W = (m3 == 0) ? wth : wph;
        f16* OUT       = (m3 == 0) ? thetaT : phiT;
        for (int ks = 0; ks < 4; ks++){
            f4v acc = {0.f, 0.f, 0.f, 0.f};
            #pragma unroll
            for (int kc = 0; kc < 4; kc++){
                const h8v af = ld8f(&W[(ks * 16 + l15) * CC + kc * 32 + quad * 8]);
                acc = __builtin_amdgcn_mfma_f32_16x16x32_f16(af, bx[kc], acc, 0, 0, 0);
            }
            h4v pv;
            #pragma unroll
            for (int r = 0; r < 4; r++) pv[r] = (f16)acc[r];
            *(h4v*)&OUT[((size_t)(b * NN + n0 + w * 16 + l15)) * CB + ks * 16 + quad * 4] = pv;
        }
    }

    // g: A = xT (n as M), B = wg (k as N = w*16+l15) -> D[row=n][col=k];
    // pack 4 consecutive n -> b64 store into gbuf[k][n]
    h8v bw[4];
    #pragma unroll
    for (int kc = 0; kc < 4; kc++)
        bw[kc] = ld8f(&wg[(w * 16 + l15) * CC + kc * 32 + quad * 8]);
    for (int ns = 0; ns < 4; ns++){
        f4v acc = {0.f, 0.f, 0.f, 0.f};
        #pragma unroll
        for (int kc = 0; kc < 4; kc++){
            const h8v af = *(const h8v*)&xT[ns * 16 + l15][kc * 32 + quad * 8];
            acc = __builtin_amdgcn_mfma_f32_16x16x32_f16(af, bw[kc], acc, 0, 0, 0);
        }
        h4v pv;
        #pragma unroll
        for (int r = 0; r < 4; r++) pv[r] = (f16)acc[r];
        *(h4v*)&gbuf[((size_t)(b * CB + w * 16 + l15)) * NN + n0 + ns * 16 + quad * 4] = pv;
    }
}

// ---------------------------------------------------------------------------
// Kernel 2: flash attention, cooperative LDS staging, TRANSPOSED-S form.
// S^T = mfma(A=phi, B=theta): lane holds 4 consecutive keys for one query
// (query = l15) -> P written as 4 ds_write_b64 (vs 16 scalar b16), softmax
// state is scalar per lane (2 cross-quad shuffles vs 16 swizzles).
// ---------------------------------------------------------------------------
__global__ __launch_bounds__(256) void attn_kernel(
    const f16* __restrict__ thetaT, const f16* __restrict__ phiT,
    const f16* __restrict__ gbuf, f16* __restrict__ yT)
{
    __shared__ __align__(16) f16 phL[2][64 * 72];   // phi chunk  [key][dim]
    __shared__ __align__(16) f16 gL [2][64 * 72];   // g   chunk  [kdim][key]
    __shared__ __align__(16) f16 plds[4][16 * 72];  // P[query][key] per wave

    const int b  = blockIdx.x & 7;                  // XCD-swizzled
    const int q0 = (blockIdx.x >> 3) << 6;
    const int t  = threadIdx.x;
    const int w = t >> 6, lane = t & 63, quad = lane >> 4, l15 = lane & 15;
    const int n0 = q0 + w * 16;

    // theta B-frags (lane l15 = query col)
    const size_t trow = ((size_t)(b * NN + n0 + l15)) * CB;
    const h8v a0 = *(const h8v*)&thetaT[trow + quad * 8];
    const h8v a1 = *(const h8v*)&thetaT[trow + 32 + quad * 8];

    // staging mapping (same as R8)
    const int r0 = t >> 3, r1 = r0 + 32, c = (t & 7) * 8;
    const f16* pphi0 = phiT + ((size_t)(b * NN + r0)) * CB + c;
    const f16* pphi1 = phiT + ((size_t)(b * NN + r1)) * CB + c;
    const f16* pg0   = gbuf + ((size_t)(b * CB + r0)) * NN + c;
    const f16* pg1   = gbuf + ((size_t)(b * CB + r1)) * NN + c;
    const int lA = r0 * 72 + c, lB = r1 * 72 + c;

    h8v nA = *(const h8v*)pphi0;
    h8v nB = *(const h8v*)pphi1;
    h8v nC = *(const h8v*)pg0;
    h8v nD = *(const h8v*)pg1;
    *(h8v*)&phL[0][lA] = nA;  *(h8v*)&phL[0][lB] = nB;
    *(h8v*)&gL [0][lA] = nC;  *(h8v*)&gL [0][lB] = nD;

    float mrun = -1e30f, lrun = 0.f;
    f4v o[4];
    const f4v zf = {0.f, 0.f, 0.f, 0.f};
    #pragma unroll
    for (int tt = 0; tt < 4; tt++) o[tt] = zf;

    f16* const pw = &plds[w][0];

    for (int kb = 0; kb < 64; kb++){
        const int pb = kb & 1;
        __syncthreads();
        if (kb < 63){
            pphi0 += (size_t)64 * CB;  pphi1 += (size_t)64 * CB;
            pg0 += 64;                 pg1 += 64;
            nA = *(const h8v*)pphi0;   nB = *(const h8v*)pphi1;
            nC = *(const h8v*)pg0;     nD = *(const h8v*)pg1;
        }

        // ---- S^T = phi(A) * theta(B): rows=keys, cols=queries ----
        f4v s[4];
        #pragma unroll
        for (int tt = 0; tt < 4; tt++){
            const f16* pr = &phL[pb][(tt * 16 + l15) * 72];
            const h8v pb0 = *(const h8v*)(pr + quad * 8);
            const h8v pb1 = *(const h8v*)(pr + 32 + quad * 8);
            f4v sv = zf;
            sv = __builtin_amdgcn_mfma_f32_16x16x32_f16(pb0, a0, sv, 0, 0, 0);
            sv = __builtin_amdgcn_mfma_f32_16x16x32_f16(pb1, a1, sv, 0, 0, 0);
            s[tt] = sv;
        }
        // ---- online softmax: lane owns query l15, 16 in-lane keys ----
        float smax = fmaxf(fmaxf(s[0][0], s[0][1]), fmaxf(s[0][2], s[0][3]));
        #pragma unroll
        for (int tt = 1; tt < 4; tt++)
            smax = fmaxf(smax, fmaxf(fmaxf(s[tt][0], s[tt][1]), fmaxf(s[tt][2], s[tt][3])));
        smax = fmaxf(smax, __shfl_xor(smax, 16));
        smax = fmaxf(smax, __shfl_xor(smax, 32));
        const float mn = fmaxf(mrun, smax);
        const float alpha = __expf(mrun - mn);
        mrun = mn;
        float lsum = 0.f;
        #pragma unroll
        for (int tt = 0; tt < 4; tt++){
            h4v pv;
            #pragma unroll
            for (int r = 0; r < 4; r++){
                float p = __expf(s[tt][r] - mn);
                lsum += p;
                pv[r] = (f16)p;
            }
            *(h4v*)&pw[l15 * 72 + tt * 16 + quad * 4] = pv;   // 4 consecutive keys
        }
        lrun = lrun * alpha + lsum;
        // redistribute alpha to o-rows (query = quad*4+r)
        float ar[4];
        #pragma unroll
        for (int r = 0; r < 4; r++) ar[r] = __shfl(alpha, quad * 4 + r);
        #pragma unroll
        for (int tt = 0; tt < 4; tt++)
            #pragma unroll
            for (int r = 0; r < 4; r++)
                o[tt][r] *= ar[r];

        // ---- reload P as A-frags (P[query][key], wave-private) ----
        const h8v pa0 = *(const h8v*)&pw[l15 * 72 + quad * 8];
        const h8v pa1 = *(const h8v*)&pw[l15 * 72 + 32 + quad * 8];

        // ---- O += P(A) * g(B) from LDS ----
        #pragma unroll
        for (int tt = 0; tt < 4; tt++){
            const f16* gr = &gL[pb][(tt * 16 + l15) * 72];
            const h8v gb0 = *(const h8v*)(gr + quad * 8);
            const h8v gb1 = *(const h8v*)(gr + 32 + quad * 8);
            o[tt] = __builtin_amdgcn_mfma_f32_16x16x32_f16(pa0, gb0, o[tt], 0, 0, 0);
            o[tt] = __builtin_amdgcn_mfma_f32_16x16x32_f16(pa1, gb1, o[tt], 0, 0, 0);
        }

        if (kb < 63){
            const int nb = pb ^ 1;
            *(h8v*)&phL[nb][lA] = nA;  *(h8v*)&phL[nb][lB] = nB;
            *(h8v*)&gL [nb][lA] = nC;  *(h8v*)&gL [nb][lB] = nD;
        }
    }

    // final denominator: sum across quads (lane-private partial is full 16-key sums)
    lrun += __shfl_xor(lrun, 16);
    lrun += __shfl_xor(lrun, 32);
    const float inv = 1.0f / lrun;
    float ir[4];
    #pragma unroll
    for (int r = 0; r < 4; r++) ir[r] = __shfl(inv, quad * 4 + r);
    #pragma unroll
    for (int tt = 0; tt < 4; tt++){
        #pragma unroll
        for (int r = 0; r < 4; r++){
            int q = quad * 4 + r;
            yT[((size_t)(b * NN + n0 + q)) * CB + tt * 16 + l15] = (f16)(o[tt][r] * ir[r]);
        }
    }
}

// ---------------------------------------------------------------------------
// Kernel 3: out = w_last * y + x. A = yT (rows = n) -> float4 residual loads
// and float4 stores (16 vector VMEM/thread vs 80 mostly-scalar).
// ---------------------------------------------------------------------------
__global__ __launch_bounds__(256) void out_kernel(
    const float* __restrict__ wl, const f16* __restrict__ yT,
    const float* __restrict__ x, float* __restrict__ out)
{
    const int b  = blockIdx.x & 7;          // XCD-swizzled
    const int n0 = (blockIdx.x >> 3) << 6;
    const int t  = threadIdx.x;
    const int w = t >> 6, lane = t & 63, quad = lane >> 4, l15 = lane & 15;

    // B-frags: wl rows (c = (w*2+cs)*16 + l15 as N)
    h8v bw[2][2];
    #pragma unroll
    for (int cs = 0; cs < 2; cs++)
        #pragma unroll
        for (int kc = 0; kc < 2; kc++)
            bw[cs][kc] = ld8f(&wl[((w * 2 + cs) * 16 + l15) * CB + kc * 32 + quad * 8]);

    #pragma unroll
    for (int ns = 0; ns < 4; ns++){
        const size_t yrow = ((size_t)(b * NN + n0 + ns * 16 + l15)) * CB;
        const h8v ya0 = *(const h8v*)&yT[yrow + quad * 8];
        const h8v ya1 = *(const h8v*)&yT[yrow + 32 + quad * 8];
        #pragma unroll
        for (int cs = 0; cs < 2; cs++){
            f4v acc = {0.f, 0.f, 0.f, 0.f};
            acc = __builtin_amdgcn_mfma_f32_16x16x32_f16(ya0, bw[cs][0], acc, 0, 0, 0);
            acc = __builtin_amdgcn_mfma_f32_16x16x32_f16(ya1, bw[cs][1], acc, 0, 0, 0);
            const int cidx = (w * 2 + cs) * 16 + l15;
            const size_t idx = ((size_t)(b * CC + cidx)) * NN + n0 + ns * 16 + quad * 4;
            const f4v xv = *(const f4v*)&x[idx];
            f4v ov;
            #pragma unroll
            for (int r = 0; r < 4; r++) ov[r] = acc[r] + xv[r];
            *(f4v*)&out[idx] = ov;
        }
    }
}

extern "C" void kernel_launch(void* const* d_in, const int* in_sizes, int n_in,
                              void* d_out, int out_size, void* d_ws, size_t ws_size,
                              hipStream_t stream)
{
    const float* x   = (const float*)d_in[0];
    const float* wth = (const float*)d_in[1];
    const float* wph = (const float*)d_in[2];
    const float* wg  = (const float*)d_in[3];
    const float* wl  = (const float*)d_in[4];
    float* out = (float*)d_out;

    f16* thetaT = (f16*)d_ws;
    f16* phiT   = thetaT + (size_t)NB * NN * CB;
    f16* gbuf   = phiT   + (size_t)NB * NN * CB;
    f16* yT     = gbuf   + (size_t)NB * NN * CB;

    proj_kernel<<<NB * 64, 256, 0, stream>>>(x, wth, wph, wg, thetaT, phiT, gbuf);
    attn_kernel<<<NB * 64, 256, 0, stream>>>(thetaT, phiT, gbuf, yT);
    out_kernel <<<NB * 64, 256, 0, stream>>>(wl, yT, x, out);
}

// Round 10
// 181.241 us; speedup vs baseline: 2.1681x; 1.0201x over previous
//
#include <hip/hip_runtime.h>
#include <stdint.h>

typedef _Float16 h8v __attribute__((ext_vector_type(8)));
typedef _Float16 h4v __attribute__((ext_vector_type(4)));
typedef float f4v __attribute__((ext_vector_type(4)));
typedef _Float16 f16;

#define NB 8
#define CC 128
#define CB 64
#define NN 4096
#define L2E 1.4426950408889634f

// load 8 consecutive fp32, convert to fp16 MFMA fragment (two 16B loads)
__device__ __forceinline__ h8v ld8f(const float* __restrict__ p){
    const f4v a = *(const f4v*)p;
    const f4v b = *(const f4v*)(p + 4);
    h8v r;
    r[0] = (f16)a[0]; r[1] = (f16)a[1]; r[2] = (f16)a[2]; r[3] = (f16)a[3];
    r[4] = (f16)b[0]; r[5] = (f16)b[1]; r[6] = (f16)b[2]; r[7] = (f16)b[3];
    return r;
}

// ---------------------------------------------------------------------------
// Kernel 1: projections. Epilogue repacks C/D fragments through a
// wave-private LDS tile (no barriers) so every global store is a full
// 128B-line h8v (8 lanes x 16B contiguous). theta pre-scaled by log2(e)
// so attn can use exp2 directly.
// ---------------------------------------------------------------------------
__global__ __launch_bounds__(256) void proj_kernel(
    const float* __restrict__ x, const float* __restrict__ wth,
    const float* __restrict__ wph, const float* __restrict__ wg,
    f16* __restrict__ thetaT, f16* __restrict__ phiT, f16* __restrict__ gbuf)
{
    __shared__ __align__(16) f16 xT[64][136];
    __shared__ __align__(16) f16 rep[4][16 * 72];   // wave-private repack tile
    const int b  = blockIdx.x & 7;          // XCD-swizzled (batch -> XCD)
    const int n0 = (blockIdx.x >> 3) << 6;
    const int t  = threadIdx.x;

    #pragma unroll
    for (int i = 0; i < 8; i++){
        int v  = t + 256 * i;
        int c  = v >> 4;
        int j0 = (v & 15) << 2;
        const f4v xv = *(const f4v*)&x[((size_t)(b * CC + c)) * NN + n0 + j0];
        #pragma unroll
        for (int jj = 0; jj < 4; jj++) xT[j0 + jj][c] = (f16)xv[jj];
    }
    __syncthreads();

    const int w = t >> 6, lane = t & 63, quad = lane >> 4, l15 = lane & 15;
    const int rrow = lane >> 3, rcol = (lane & 7) * 8;   // repack read map

    // B-frags from xT (n = w*16 + l15) for theta/phi
    h8v bx[4];
    #pragma unroll
    for (int kc = 0; kc < 4; kc++)
        bx[kc] = *(const h8v*)&xT[w * 16 + l15][kc * 32 + quad * 8];

    // theta & phi: A = W rows (k as M) -> D[row=k][col=n]
    #pragma unroll
    for (int m3 = 0; m3 < 2; m3++){
        const float* W = (m3 == 0) ? wth : wph;
        f16* OUT       = (m3 == 0) ? thetaT : phiT;
        const float sc = (m3 == 0) ? L2E : 1.0f;
        for (int ks = 0; ks < 4; ks++){
            f4v acc = {0.f, 0.f, 0.f, 0.f};
            #pragma unroll
            for (int kc = 0; kc < 4; kc++){
                const h8v af = ld8f(&W[(ks * 16 + l15) * CC + kc * 32 + quad * 8]);
                acc = __builtin_amdgcn_mfma_f32_16x16x32_f16(af, bx[kc], acc, 0, 0, 0);
            }
            h4v pv;
            #pragma unroll
            for (int r = 0; r < 4; r++) pv[r] = (f16)(acc[r] * sc);
            *(h4v*)&rep[w][l15 * 72 + ks * 16 + quad * 4] = pv;
        }
        // wave-private LDS -> coalesced full-line stores (rows n)
        #pragma unroll
        for (int j = 0; j < 2; j++){
            const h8v vv = *(const h8v*)&rep[w][(rrow + 8 * j) * 72 + rcol];
            *(h8v*)&OUT[((size_t)(b * NN + n0 + w * 16 + rrow + 8 * j)) * CB + rcol] = vv;
        }
    }

    // g: A = xT (n as M), B = wg (k as N) -> D[row=n][col=k=w*16+l15]
    h8v bw[4];
    #pragma unroll
    for (int kc = 0; kc < 4; kc++)
        bw[kc] = ld8f(&wg[(w * 16 + l15) * CC + kc * 32 + quad * 8]);
    for (int ns = 0; ns < 4; ns++){
        f4v acc = {0.f, 0.f, 0.f, 0.f};
        #pragma unroll
        for (int kc = 0; kc < 4; kc++){
            const h8v af = *(const h8v*)&xT[ns * 16 + l15][kc * 32 + quad * 8];
            acc = __builtin_amdgcn_mfma_f32_16x16x32_f16(af, bw[kc], acc, 0, 0, 0);
        }
        h4v pv;
        #pragma unroll
        for (int r = 0; r < 4; r++) pv[r] = (f16)acc[r];
        *(h4v*)&rep[w][l15 * 72 + ns * 16 + quad * 4] = pv;   // row=k-local, col=n-local
    }
    #pragma unroll
    for (int j = 0; j < 2; j++){
        const h8v vv = *(const h8v*)&rep[w][(rrow + 8 * j) * 72 + rcol];
        *(h8v*)&gbuf[((size_t)(b * CB + w * 16 + rrow + 8 * j)) * NN + n0 + rcol] = vv;
    }
}

// ---------------------------------------------------------------------------
// Kernel 2: flash attention, cooperative LDS staging, transposed-S form.
// Unchanged from R9 except exp -> exp2 (theta pre-scaled by log2 e).
// ---------------------------------------------------------------------------
__global__ __launch_bounds__(256) void attn_kernel(
    const f16* __restrict__ thetaT, const f16* __restrict__ phiT,
    const f16* __restrict__ gbuf, f16* __restrict__ yT)
{
    __shared__ __align__(16) f16 phL[2][64 * 72];   // phi chunk  [key][dim]
    __shared__ __align__(16) f16 gL [2][64 * 72];   // g   chunk  [kdim][key]
    __shared__ __align__(16) f16 plds[4][16 * 72];  // P[query][key] per wave

    const int b  = blockIdx.x & 7;                  // XCD-swizzled
    const int q0 = (blockIdx.x >> 3) << 6;
    const int t  = threadIdx.x;
    const int w = t >> 6, lane = t & 63, quad = lane >> 4, l15 = lane & 15;
    const int n0 = q0 + w * 16;

    // theta B-frags (lane l15 = query col)
    const size_t trow = ((size_t)(b * NN + n0 + l15)) * CB;
    const h8v a0 = *(const h8v*)&thetaT[trow + quad * 8];
    const h8v a1 = *(const h8v*)&thetaT[trow + 32 + quad * 8];

    // staging mapping
    const int r0 = t >> 3, r1 = r0 + 32, c = (t & 7) * 8;
    const f16* pphi0 = phiT + ((size_t)(b * NN + r0)) * CB + c;
    const f16* pphi1 = phiT + ((size_t)(b * NN + r1)) * CB + c;
    const f16* pg0   = gbuf + ((size_t)(b * CB + r0)) * NN + c;
    const f16* pg1   = gbuf + ((size_t)(b * CB + r1)) * NN + c;
    const int lA = r0 * 72 + c, lB = r1 * 72 + c;

    h8v nA = *(const h8v*)pphi0;
    h8v nB = *(const h8v*)pphi1;
    h8v nC = *(const h8v*)pg0;
    h8v nD = *(const h8v*)pg1;
    *(h8v*)&phL[0][lA] = nA;  *(h8v*)&phL[0][lB] = nB;
    *(h8v*)&gL [0][lA] = nC;  *(h8v*)&gL [0][lB] = nD;

    float mrun = -1e30f, lrun = 0.f;
    f4v o[4];
    const f4v zf = {0.f, 0.f, 0.f, 0.f};
    #pragma unroll
    for (int tt = 0; tt < 4; tt++) o[tt] = zf;

    f16* const pw = &plds[w][0];

    for (int kb = 0; kb < 64; kb++){
        const int pb = kb & 1;
        __syncthreads();
        if (kb < 63){
            pphi0 += (size_t)64 * CB;  pphi1 += (size_t)64 * CB;
            pg0 += 64;                 pg1 += 64;
            nA = *(const h8v*)pphi0;   nB = *(const h8v*)pphi1;
            nC = *(const h8v*)pg0;     nD = *(const h8v*)pg1;
        }

        // ---- S^T = phi(A) * theta(B): rows=keys, cols=queries ----
        f4v s[4];
        #pragma unroll
        for (int tt = 0; tt < 4; tt++){
            const f16* pr = &phL[pb][(tt * 16 + l15) * 72];
            const h8v pb0 = *(const h8v*)(pr + quad * 8);
            const h8v pb1 = *(const h8v*)(pr + 32 + quad * 8);
            f4v sv = zf;
            sv = __builtin_amdgcn_mfma_f32_16x16x32_f16(pb0, a0, sv, 0, 0, 0);
            sv = __builtin_amdgcn_mfma_f32_16x16x32_f16(pb1, a1, sv, 0, 0, 0);
            s[tt] = sv;
        }
        // ---- online softmax (log2 domain; theta pre-scaled) ----
        float smax = fmaxf(fmaxf(s[0][0], s[0][1]), fmaxf(s[0][2], s[0][3]));
        #pragma unroll
        for (int tt = 1; tt < 4; tt++)
            smax = fmaxf(smax, fmaxf(fmaxf(s[tt][0], s[tt][1]), fmaxf(s[tt][2], s[tt][3])));
        smax = fmaxf(smax, __shfl_xor(smax, 16));
        smax = fmaxf(smax, __shfl_xor(smax, 32));
        const float mn = fmaxf(mrun, smax);
        const float alpha = __builtin_amdgcn_exp2f(mrun - mn);
        mrun = mn;
        float lsum = 0.f;
        #pragma unroll
        for (int tt = 0; tt < 4; tt++){
            h4v pv;
            #pragma unroll
            for (int r = 0; r < 4; r++){
                float p = __builtin_amdgcn_exp2f(s[tt][r] - mn);
                lsum += p;
                pv[r] = (f16)p;
            }
            *(h4v*)&pw[l15 * 72 + tt * 16 + quad * 4] = pv;   // 4 consecutive keys
        }
        lrun = lrun * alpha + lsum;
        // redistribute alpha to o-rows (query = quad*4+r)
        float ar[4];
        #pragma unroll
        for (int r = 0; r < 4; r++) ar[r] = __shfl(alpha, quad * 4 + r);
        #pragma unroll
        for (int tt = 0; tt < 4; tt++)
            #pragma unroll
            for (int r = 0; r < 4; r++)
                o[tt][r] *= ar[r];

        // ---- reload P as A-frags (P[query][key], wave-private) ----
        const h8v pa0 = *(const h8v*)&pw[l15 * 72 + quad * 8];
        const h8v pa1 = *(const h8v*)&pw[l15 * 72 + 32 + quad * 8];

        // ---- O += P(A) * g(B) from LDS ----
        #pragma unroll
        for (int tt = 0; tt < 4; tt++){
            const f16* gr = &gL[pb][(tt * 16 + l15) * 72];
            const h8v gb0 = *(const h8v*)(gr + quad * 8);
            const h8v gb1 = *(const h8v*)(gr + 32 + quad * 8);
            o[tt] = __builtin_amdgcn_mfma_f32_16x16x32_f16(pa0, gb0, o[tt], 0, 0, 0);
            o[tt] = __builtin_amdgcn_mfma_f32_16x16x32_f16(pa1, gb1, o[tt], 0, 0, 0);
        }

        if (kb < 63){
            const int nb = pb ^ 1;
            *(h8v*)&phL[nb][lA] = nA;  *(h8v*)&phL[nb][lB] = nB;
            *(h8v*)&gL [nb][lA] = nC;  *(h8v*)&gL [nb][lB] = nD;
        }
    }

    // final denominator: sum across quads
    lrun += __shfl_xor(lrun, 16);
    lrun += __shfl_xor(lrun, 32);
    const float inv = 1.0f / lrun;
    float ir[4];
    #pragma unroll
    for (int r = 0; r < 4; r++) ir[r] = __shfl(inv, quad * 4 + r);
    #pragma unroll
    for (int tt = 0; tt < 4; tt++){
        #pragma unroll
        for (int r = 0; r < 4; r++){
            int q = quad * 4 + r;
            yT[((size_t)(b * NN + n0 + q)) * CB + tt * 16 + l15] = (f16)(o[tt][r] * ir[r]);
        }
    }
}

// ---------------------------------------------------------------------------
// Kernel 3: out = w_last * y + x. Wave-private LDS repack -> fully coalesced
// float4 x-loads and out-stores (16 lanes cover a 256B row).
// ---------------------------------------------------------------------------
__global__ __launch_bounds__(256) void out_kernel(
    const float* __restrict__ wl, const f16* __restrict__ yT,
    const float* __restrict__ x, float* __restrict__ out)
{
    __shared__ __align__(16) float ldsO[4][32 * 68];   // wave-private [c][n] tile
    const int b  = blockIdx.x & 7;          // XCD-swizzled
    const int n0 = (blockIdx.x >> 3) << 6;
    const int t  = threadIdx.x;
    const int w = t >> 6, lane = t & 63, quad = lane >> 4, l15 = lane & 15;

    // B-frags: wl rows (c = (w*2+cs)*16 + l15 as N)
    h8v bw[2][2];
    #pragma unroll
    for (int cs = 0; cs < 2; cs++)
        #pragma unroll
        for (int kc = 0; kc < 2; kc++)
            bw[cs][kc] = ld8f(&wl[((w * 2 + cs) * 16 + l15) * CB + kc * 32 + quad * 8]);

    #pragma unroll
    for (int ns = 0; ns < 4; ns++){
        const size_t yrow = ((size_t)(b * NN + n0 + ns * 16 + l15)) * CB;
        const h8v ya0 = *(const h8v*)&yT[yrow + quad * 8];
        const h8v ya1 = *(const h8v*)&yT[yrow + 32 + quad * 8];
        #pragma unroll
        for (int cs = 0; cs < 2; cs++){
            f4v acc = {0.f, 0.f, 0.f, 0.f};
            acc = __builtin_amdgcn_mfma_f32_16x16x32_f16(ya0, bw[cs][0], acc, 0, 0, 0);
            acc = __builtin_amdgcn_mfma_f32_16x16x32_f16(ya1, bw[cs][1], acc, 0, 0, 0);
            // C/D: row = n-local (ns*16+quad*4..+3), col = c-local (cs*16+l15)
            *(f4v*)&ldsO[w][(cs * 16 + l15) * 68 + ns * 16 + quad * 4] = acc;
        }
    }
    // wave-private: no barrier. Coalesced read-modify-write epilogue.
    #pragma unroll
    for (int i = 0; i < 8; i++){
        const int row = i * 4 + (lane >> 4);        // 0..31 (c-local)
        const int cseg = (lane & 15) * 4;           // n-local float offset
        const f4v v = *(const f4v*)&ldsO[w][row * 68 + cseg];
        const size_t idx = ((size_t)(b * CC + w * 32 + row)) * NN + n0 + cseg;
        const f4v xv = *(const f4v*)&x[idx];
        f4v ov;
        #pragma unroll
        for (int r = 0; r < 4; r++) ov[r] = v[r] + xv[r];
        *(f4v*)&out[idx] = ov;
    }
}

extern "C" void kernel_launch(void* const* d_in, const int* in_sizes, int n_in,
                              void* d_out, int out_size, void* d_ws, size_t ws_size,
                              hipStream_t stream)
{
    const float* x   = (const float*)d_in[0];
    const float* wth = (const float*)d_in[1];
    const float* wph = (const float*)d_in[2];
    const float* wg  = (const float*)d_in[3];
    const float* wl  = (const float*)d_in[4];
    float* out = (float*)d_out;

    f16* thetaT = (f16*)d_ws;
    f16* phiT   = thetaT + (size_t)NB * NN * CB;
    f16* gbuf   = phiT   + (size_t)NB * NN * CB;
    f16* yT     = gbuf   + (size_t)NB * NN * CB;

    proj_kernel<<<NB * 64, 256, 0, stream>>>(x, wth, wph, wg, thetaT, phiT, gbuf);
    attn_kernel<<<NB * 64, 256, 0, stream>>>(thetaT, phiT, gbuf, yT);
    out_kernel <<<NB * 64, 256, 0, stream>>>(wl, yT, x, out);
}

// Round 11
// 174.513 us; speedup vs baseline: 2.2516x; 1.0386x over previous
//
#include <hip/hip_runtime.h>
#include <stdint.h>

typedef _Float16 h8v __attribute__((ext_vector_type(8)));
typedef _Float16 h4v __attribute__((ext_vector_type(4)));
typedef float f4v __attribute__((ext_vector_type(4)));
typedef _Float16 f16;

#define NB 8
#define CC 128
#define CB 64
#define NN 4096
#define L2E 1.4426950408889634f

// load 8 consecutive fp32, convert to fp16 MFMA fragment (two 16B loads)
__device__ __forceinline__ h8v ld8f(const float* __restrict__ p){
    const f4v a = *(const f4v*)p;
    const f4v b = *(const f4v*)(p + 4);
    h8v r;
    r[0] = (f16)a[0]; r[1] = (f16)a[1]; r[2] = (f16)a[2]; r[3] = (f16)a[3];
    r[4] = (f16)b[0]; r[5] = (f16)b[1]; r[6] = (f16)b[2]; r[7] = (f16)b[3];
    return r;
}

// ---------------------------------------------------------------------------
// Kernel 1: projections (unchanged from R10). theta pre-scaled by log2(e).
// ---------------------------------------------------------------------------
__global__ __launch_bounds__(256) void proj_kernel(
    const float* __restrict__ x, const float* __restrict__ wth,
    const float* __restrict__ wph, const float* __restrict__ wg,
    f16* __restrict__ thetaT, f16* __restrict__ phiT, f16* __restrict__ gbuf)
{
    __shared__ __align__(16) f16 xT[64][136];
    __shared__ __align__(16) f16 rep[4][16 * 72];
    const int b  = blockIdx.x & 7;
    const int n0 = (blockIdx.x >> 3) << 6;
    const int t  = threadIdx.x;

    #pragma unroll
    for (int i = 0; i < 8; i++){
        int v  = t + 256 * i;
        int c  = v >> 4;
        int j0 = (v & 15) << 2;
        const f4v xv = *(const f4v*)&x[((size_t)(b * CC + c)) * NN + n0 + j0];
        #pragma unroll
        for (int jj = 0; jj < 4; jj++) xT[j0 + jj][c] = (f16)xv[jj];
    }
    __syncthreads();

    const int w = t >> 6, lane = t & 63, quad = lane >> 4, l15 = lane & 15;
    const int rrow = lane >> 3, rcol = (lane & 7) * 8;

    h8v bx[4];
    #pragma unroll
    for (int kc = 0; kc < 4; kc++)
        bx[kc] = *(const h8v*)&xT[w * 16 + l15][kc * 32 + quad * 8];

    #pragma unroll
    for (int m3 = 0; m3 < 2; m3++){
        const float* W = (m3 == 0) ? wth : wph;
        f16* OUT       = (m3 == 0) ? thetaT : phiT;
        const float sc = (m3 == 0) ? L2E : 1.0f;
        for (int ks = 0; ks < 4; ks++){
            f4v acc = {0.f, 0.f, 0.f, 0.f};
            #pragma unroll
            for (int kc = 0; kc < 4; kc++){
                const h8v af = ld8f(&W[(ks * 16 + l15) * CC + kc * 32 + quad * 8]);
                acc = __builtin_amdgcn_mfma_f32_16x16x32_f16(af, bx[kc], acc, 0, 0, 0);
            }
            h4v pv;
            #pragma unroll
            for (int r = 0; r < 4; r++) pv[r] = (f16)(acc[r] * sc);
            *(h4v*)&rep[w][l15 * 72 + ks * 16 + quad * 4] = pv;
        }
        #pragma unroll
        for (int j = 0; j < 2; j++){
            const h8v vv = *(const h8v*)&rep[w][(rrow + 8 * j) * 72 + rcol];
            *(h8v*)&OUT[((size_t)(b * NN + n0 + w * 16 + rrow + 8 * j)) * CB + rcol] = vv;
        }
    }

    h8v bw[4];
    #pragma unroll
    for (int kc = 0; kc < 4; kc++)
        bw[kc] = ld8f(&wg[(w * 16 + l15) * CC + kc * 32 + quad * 8]);
    for (int ns = 0; ns < 4; ns++){
        f4v acc = {0.f, 0.f, 0.f, 0.f};
        #pragma unroll
        for (int kc = 0; kc < 4; kc++){
            const h8v af = *(const h8v*)&xT[ns * 16 + l15][kc * 32 + quad * 8];
            acc = __builtin_amdgcn_mfma_f32_16x16x32_f16(af, bw[kc], acc, 0, 0, 0);
        }
        h4v pv;
        #pragma unroll
        for (int r = 0; r < 4; r++) pv[r] = (f16)acc[r];
        *(h4v*)&rep[w][l15 * 72 + ns * 16 + quad * 4] = pv;
    }
    #pragma unroll
    for (int j = 0; j < 2; j++){
        const h8v vv = *(const h8v*)&rep[w][(rrow + 8 * j) * 72 + rcol];
        *(h8v*)&gbuf[((size_t)(b * CB + w * 16 + rrow + 8 * j)) * NN + n0 + rcol] = vv;
    }
}

// ---------------------------------------------------------------------------
// Kernel 2: fused attention + final projection + residual.
// K-loop: transposed-S AND transposed-PV (operand swaps only) so O cols =
// query = l15 -> alpha/normalize are lane-local scalars. Epilogue: y tile ->
// wave-private LDS (4 b64 writes), out-GEMM vs w_last (16 MFMAs/wave) into a
// block f32 [128c][64n] tile overlaid on the dead phi/g staging LDS, then
// fully-coalesced float4 residual RMW. Eliminates out_kernel + yT traffic.
// ---------------------------------------------------------------------------
union StageOrOut {
    struct { f16 ph[2][64 * 72]; f16 g[2][64 * 72]; } s;   // 36864 B (K-loop)
    float fO[128][68];                                      // 34816 B (epilogue)
};

__global__ __launch_bounds__(256) void attn_kernel(
    const f16* __restrict__ thetaT, const f16* __restrict__ phiT,
    const f16* __restrict__ gbuf, const float* __restrict__ wl,
    const float* __restrict__ x, float* __restrict__ out)
{
    __shared__ __align__(16) StageOrOut sh;
    __shared__ __align__(16) f16 plds[4][16 * 72];  // P tile, then y tile

    const int b  = blockIdx.x & 7;                  // XCD-swizzled
    const int q0 = (blockIdx.x >> 3) << 6;
    const int t  = threadIdx.x;
    const int w = t >> 6, lane = t & 63, quad = lane >> 4, l15 = lane & 15;
    const int n0 = q0 + w * 16;

    // theta B-frags (lane l15 = query col)
    const size_t trow = ((size_t)(b * NN + n0 + l15)) * CB;
    const h8v a0 = *(const h8v*)&thetaT[trow + quad * 8];
    const h8v a1 = *(const h8v*)&thetaT[trow + 32 + quad * 8];

    // staging mapping
    const int r0 = t >> 3, r1 = r0 + 32, c = (t & 7) * 8;
    const f16* pphi0 = phiT + ((size_t)(b * NN + r0)) * CB + c;
    const f16* pphi1 = phiT + ((size_t)(b * NN + r1)) * CB + c;
    const f16* pg0   = gbuf + ((size_t)(b * CB + r0)) * NN + c;
    const f16* pg1   = gbuf + ((size_t)(b * CB + r1)) * NN + c;
    const int lA = r0 * 72 + c, lB = r1 * 72 + c;

    h8v nA = *(const h8v*)pphi0;
    h8v nB = *(const h8v*)pphi1;
    h8v nC = *(const h8v*)pg0;
    h8v nD = *(const h8v*)pg1;
    *(h8v*)&sh.s.ph[0][lA] = nA;  *(h8v*)&sh.s.ph[0][lB] = nB;
    *(h8v*)&sh.s.g [0][lA] = nC;  *(h8v*)&sh.s.g [0][lB] = nD;

    float mrun = -1e30f, lrun = 0.f;
    f4v o[4];                        // o[tt][r] = y^T[kd=tt*16+quad*4+r][q=l15]
    const f4v zf = {0.f, 0.f, 0.f, 0.f};
    #pragma unroll
    for (int tt = 0; tt < 4; tt++) o[tt] = zf;

    f16* const pw = &plds[w][0];

    for (int kb = 0; kb < 64; kb++){
        const int pb = kb & 1;
        __syncthreads();
        if (kb < 63){
            pphi0 += (size_t)64 * CB;  pphi1 += (size_t)64 * CB;
            pg0 += 64;                 pg1 += 64;
            nA = *(const h8v*)pphi0;   nB = *(const h8v*)pphi1;
            nC = *(const h8v*)pg0;     nD = *(const h8v*)pg1;
        }

        // ---- S^T = phi(A) * theta(B): rows=keys, cols=queries ----
        f4v s[4];
        #pragma unroll
        for (int tt = 0; tt < 4; tt++){
            const f16* pr = &sh.s.ph[pb][(tt * 16 + l15) * 72];
            const h8v pb0 = *(const h8v*)(pr + quad * 8);
            const h8v pb1 = *(const h8v*)(pr + 32 + quad * 8);
            f4v sv = zf;
            sv = __builtin_amdgcn_mfma_f32_16x16x32_f16(pb0, a0, sv, 0, 0, 0);
            sv = __builtin_amdgcn_mfma_f32_16x16x32_f16(pb1, a1, sv, 0, 0, 0);
            s[tt] = sv;
        }
        // ---- online softmax (log2 domain; lane owns query l15) ----
        float smax = fmaxf(fmaxf(s[0][0], s[0][1]), fmaxf(s[0][2], s[0][3]));
        #pragma unroll
        for (int tt = 1; tt < 4; tt++)
            smax = fmaxf(smax, fmaxf(fmaxf(s[tt][0], s[tt][1]), fmaxf(s[tt][2], s[tt][3])));
        smax = fmaxf(smax, __shfl_xor(smax, 16));
        smax = fmaxf(smax, __shfl_xor(smax, 32));
        const float mn = fmaxf(mrun, smax);
        const float alpha = __builtin_amdgcn_exp2f(mrun - mn);
        mrun = mn;
        float lsum = 0.f;
        #pragma unroll
        for (int tt = 0; tt < 4; tt++){
            h4v pv;
            #pragma unroll
            for (int r = 0; r < 4; r++){
                float p = __builtin_amdgcn_exp2f(s[tt][r] - mn);
                lsum += p;
                pv[r] = (f16)p;
            }
            *(h4v*)&pw[l15 * 72 + tt * 16 + quad * 4] = pv;
        }
        lrun = lrun * alpha + lsum;
        // O rescale: alpha is lane-local (cols = query = l15)
        #pragma unroll
        for (int tt = 0; tt < 4; tt++)
            #pragma unroll
            for (int r = 0; r < 4; r++)
                o[tt][r] *= alpha;

        // ---- reload P as B-frags (same addresses as before) ----
        const h8v pa0 = *(const h8v*)&pw[l15 * 72 + quad * 8];
        const h8v pa1 = *(const h8v*)&pw[l15 * 72 + 32 + quad * 8];

        // ---- O^T += g(A) * P^T(B): operand-swapped PV ----
        #pragma unroll
        for (int tt = 0; tt < 4; tt++){
            const f16* gr = &sh.s.g[pb][(tt * 16 + l15) * 72];
            const h8v gb0 = *(const h8v*)(gr + quad * 8);
            const h8v gb1 = *(const h8v*)(gr + 32 + quad * 8);
            o[tt] = __builtin_amdgcn_mfma_f32_16x16x32_f16(gb0, pa0, o[tt], 0, 0, 0);
            o[tt] = __builtin_amdgcn_mfma_f32_16x16x32_f16(gb1, pa1, o[tt], 0, 0, 0);
        }

        if (kb < 63){
            const int nb = pb ^ 1;
            *(h8v*)&sh.s.ph[nb][lA] = nA;  *(h8v*)&sh.s.ph[nb][lB] = nB;
            *(h8v*)&sh.s.g [nb][lA] = nC;  *(h8v*)&sh.s.g [nb][lB] = nD;
        }
    }

    // ---- normalize: lrun reduce across quads, inv lane-local ----
    lrun += __shfl_xor(lrun, 16);
    lrun += __shfl_xor(lrun, 32);
    const float inv = 1.0f / lrun;

    // y tile -> wave-private LDS (reuse plds): yL[q=l15][kd], packed b64
    #pragma unroll
    for (int tt = 0; tt < 4; tt++){
        h4v yv;
        #pragma unroll
        for (int r = 0; r < 4; r++) yv[r] = (f16)(o[tt][r] * inv);
        *(h4v*)&pw[l15 * 72 + tt * 16 + quad * 4] = yv;
    }

    __syncthreads();   // staging region dead for ALL waves -> safe to overlay fO

    // ---- out-GEMM: D[c][q] = wl(A) * y(B); 16 MFMAs/wave ----
    const h8v yB0 = *(const h8v*)&pw[l15 * 72 + quad * 8];
    const h8v yB1 = *(const h8v*)&pw[l15 * 72 + 32 + quad * 8];
    #pragma unroll
    for (int cs = 0; cs < 8; cs++){
        const h8v wa0 = ld8f(&wl[(cs * 16 + l15) * CB + quad * 8]);
        const h8v wa1 = ld8f(&wl[(cs * 16 + l15) * CB + 32 + quad * 8]);
        f4v acc = zf;
        acc = __builtin_amdgcn_mfma_f32_16x16x32_f16(wa0, yB0, acc, 0, 0, 0);
        acc = __builtin_amdgcn_mfma_f32_16x16x32_f16(wa1, yB1, acc, 0, 0, 0);
        #pragma unroll
        for (int r = 0; r < 4; r++)
            sh.fO[cs * 16 + quad * 4 + r][w * 16 + l15] = acc[r];
    }
    __syncthreads();

    // ---- residual RMW: fully coalesced float4 (16 lanes = 256B row seg) ----
    #pragma unroll
    for (int i = 0; i < 8; i++){
        const int row = i * 16 + (t >> 4);
        const int nf  = (t & 15) * 4;
        const f4v v = *(const f4v*)&sh.fO[row][nf];
        const size_t idx = ((size_t)(b * CC + row)) * NN + q0 + nf;
        const f4v xv = *(const f4v*)&x[idx];
        f4v ov;
        #pragma unroll
        for (int r = 0; r < 4; r++) ov[r] = v[r] + xv[r];
        *(f4v*)&out[idx] = ov;
    }
}

extern "C" void kernel_launch(void* const* d_in, const int* in_sizes, int n_in,
                              void* d_out, int out_size, void* d_ws, size_t ws_size,
                              hipStream_t stream)
{
    const float* x   = (const float*)d_in[0];
    const float* wth = (const float*)d_in[1];
    const float* wph = (const float*)d_in[2];
    const float* wg  = (const float*)d_in[3];
    const float* wl  = (const float*)d_in[4];
    float* out = (float*)d_out;

    f16* thetaT = (f16*)d_ws;
    f16* phiT   = thetaT + (size_t)NB * NN * CB;
    f16* gbuf   = phiT   + (size_t)NB * NN * CB;

    proj_kernel<<<NB * 64, 256, 0, stream>>>(x, wth, wph, wg, thetaT, phiT, gbuf);
    attn_kernel<<<NB * 64, 256, 0, stream>>>(thetaT, phiT, gbuf, wl, x, out);
}

// Round 13
// 158.718 us; speedup vs baseline: 2.4757x; 1.0995x over previous
//
#include <hip/hip_runtime.h>
#include <stdint.h>

typedef _Float16 h8v __attribute__((ext_vector_type(8)));
typedef _Float16 h4v __attribute__((ext_vector_type(4)));
typedef float f4v __attribute__((ext_vector_type(4)));
typedef _Float16 f16;

#define NB 8
#define CC 128
#define CB 64
#define NN 4096
#define L2E 1.4426950408889634f

// ---------------------------------------------------------------------------
// Kernel 0: pack weights into f16 MFMA-fragment order (once per launch).
// Wp[((ks*4+kc)*64 + lane)*8 + j] <- W[(ks*16+(lane&15))*CC + kc*32+((lane>>4)&3)*8 + j]
// Each 64x128 weight = 8192 f16 (R12 bug: was sized/looped at 4096 = half).
// wth pre-scaled by log2(e) for attn's exp2 softmax.
// ---------------------------------------------------------------------------
__global__ __launch_bounds__(256) void pack_w(
    const float* __restrict__ wth, const float* __restrict__ wph,
    const float* __restrict__ wg,  const float* __restrict__ wl,
    f16* __restrict__ wthp, f16* __restrict__ wphp,
    f16* __restrict__ wgp,  f16* __restrict__ wlp)
{
    const int t = blockIdx.x * 256 + threadIdx.x;      // 2048 threads
    for (int i = t; i < 8192; i += 2048){
        const int j = i & 7, lane = (i >> 3) & 63, kc = (i >> 9) & 3, ks = i >> 11;
        const int row = ks * 16 + (lane & 15);
        const int col = kc * 32 + ((lane >> 4) & 3) * 8 + j;
        wthp[i] = (f16)(wth[row * CC + col] * L2E);
        wphp[i] = (f16)(wph[row * CC + col]);
        wgp [i] = (f16)(wg [row * CC + col]);
    }
    for (int i = t; i < 8192; i += 2048){
        const int j = i & 7, lane = (i >> 3) & 63, kc = (i >> 9) & 1, cs = i >> 10;
        const int row = cs * 16 + (lane & 15);
        const int col = kc * 32 + ((lane >> 4) & 3) * 8 + j;
        wlp[i] = (f16)(wl[row * CB + col]);
    }
}

// ---------------------------------------------------------------------------
// Kernel 1: projections. All weight fragments from packed f16 buffers
// (coalesced, L1-resident). Epilogue repack via wave-private LDS.
// ---------------------------------------------------------------------------
__global__ __launch_bounds__(256) void proj_kernel(
    const float* __restrict__ x, const f16* __restrict__ wthp,
    const f16* __restrict__ wphp, const f16* __restrict__ wgp,
    f16* __restrict__ thetaT, f16* __restrict__ phiT, f16* __restrict__ gbuf)
{
    __shared__ __align__(16) f16 xT[64][136];
    __shared__ __align__(16) f16 rep[4][16 * 72];
    const int b  = blockIdx.x & 7;
    const int n0 = (blockIdx.x >> 3) << 6;
    const int t  = threadIdx.x;

    #pragma unroll
    for (int i = 0; i < 8; i++){
        int v  = t + 256 * i;
        int c  = v >> 4;
        int j0 = (v & 15) << 2;
        const f4v xv = *(const f4v*)&x[((size_t)(b * CC + c)) * NN + n0 + j0];
        #pragma unroll
        for (int jj = 0; jj < 4; jj++) xT[j0 + jj][c] = (f16)xv[jj];
    }
    __syncthreads();

    const int w = t >> 6, lane = t & 63, quad = lane >> 4, l15 = lane & 15;
    const int rrow = lane >> 3, rcol = (lane & 7) * 8;

    h8v bx[4];
    #pragma unroll
    for (int kc = 0; kc < 4; kc++)
        bx[kc] = *(const h8v*)&xT[w * 16 + l15][kc * 32 + quad * 8];

    #pragma unroll
    for (int m3 = 0; m3 < 2; m3++){
        const f16* WP = (m3 == 0) ? wthp : wphp;
        f16* OUT      = (m3 == 0) ? thetaT : phiT;
        for (int ks = 0; ks < 4; ks++){
            f4v acc = {0.f, 0.f, 0.f, 0.f};
            #pragma unroll
            for (int kc = 0; kc < 4; kc++){
                const h8v af = *(const h8v*)&WP[(ks * 4 + kc) * 512 + lane * 8];
                acc = __builtin_amdgcn_mfma_f32_16x16x32_f16(af, bx[kc], acc, 0, 0, 0);
            }
            h4v pv;
            #pragma unroll
            for (int r = 0; r < 4; r++) pv[r] = (f16)acc[r];
            *(h4v*)&rep[w][l15 * 72 + ks * 16 + quad * 4] = pv;
        }
        #pragma unroll
        for (int j = 0; j < 2; j++){
            const h8v vv = *(const h8v*)&rep[w][(rrow + 8 * j) * 72 + rcol];
            *(h8v*)&OUT[((size_t)(b * NN + n0 + w * 16 + rrow + 8 * j)) * CB + rcol] = vv;
        }
    }

    h8v bw[4];
    #pragma unroll
    for (int kc = 0; kc < 4; kc++)
        bw[kc] = *(const h8v*)&wgp[(w * 4 + kc) * 512 + lane * 8];
    for (int ns = 0; ns < 4; ns++){
        f4v acc = {0.f, 0.f, 0.f, 0.f};
        #pragma unroll
        for (int kc = 0; kc < 4; kc++){
            const h8v af = *(const h8v*)&xT[ns * 16 + l15][kc * 32 + quad * 8];
            acc = __builtin_amdgcn_mfma_f32_16x16x32_f16(af, bw[kc], acc, 0, 0, 0);
        }
        h4v pv;
        #pragma unroll
        for (int r = 0; r < 4; r++) pv[r] = (f16)acc[r];
        *(h4v*)&rep[w][l15 * 72 + ns * 16 + quad * 4] = pv;
    }
    #pragma unroll
    for (int j = 0; j < 2; j++){
        const h8v vv = *(const h8v*)&rep[w][(rrow + 8 * j) * 72 + rcol];
        *(h8v*)&gbuf[((size_t)(b * CB + w * 16 + rrow + 8 * j)) * NN + n0 + rcol] = vv;
    }
}

// ---------------------------------------------------------------------------
// Kernel 2: fused attention + final projection + residual (R11 structure;
// wl loads from packed buffer).
// ---------------------------------------------------------------------------
union StageOrOut {
    struct { f16 ph[2][64 * 72]; f16 g[2][64 * 72]; } s;   // 36864 B (K-loop)
    float fO[128][68];                                      // 34816 B (epilogue)
};

__global__ __launch_bounds__(256) void attn_kernel(
    const f16* __restrict__ thetaT, const f16* __restrict__ phiT,
    const f16* __restrict__ gbuf, const f16* __restrict__ wlp,
    const float* __restrict__ x, float* __restrict__ out)
{
    __shared__ __align__(16) StageOrOut sh;
    __shared__ __align__(16) f16 plds[4][16 * 72];  // P tile, then y tile

    const int b  = blockIdx.x & 7;                  // XCD-swizzled
    const int q0 = (blockIdx.x >> 3) << 6;
    const int t  = threadIdx.x;
    const int w = t >> 6, lane = t & 63, quad = lane >> 4, l15 = lane & 15;
    const int n0 = q0 + w * 16;

    const size_t trow = ((size_t)(b * NN + n0 + l15)) * CB;
    const h8v a0 = *(const h8v*)&thetaT[trow + quad * 8];
    const h8v a1 = *(const h8v*)&thetaT[trow + 32 + quad * 8];

    const int r0 = t >> 3, r1 = r0 + 32, c = (t & 7) * 8;
    const f16* pphi0 = phiT + ((size_t)(b * NN + r0)) * CB + c;
    const f16* pphi1 = phiT + ((size_t)(b * NN + r1)) * CB + c;
    const f16* pg0   = gbuf + ((size_t)(b * CB + r0)) * NN + c;
    const f16* pg1   = gbuf + ((size_t)(b * CB + r1)) * NN + c;
    const int lA = r0 * 72 + c, lB = r1 * 72 + c;

    h8v nA = *(const h8v*)pphi0;
    h8v nB = *(const h8v*)pphi1;
    h8v nC = *(const h8v*)pg0;
    h8v nD = *(const h8v*)pg1;
    *(h8v*)&sh.s.ph[0][lA] = nA;  *(h8v*)&sh.s.ph[0][lB] = nB;
    *(h8v*)&sh.s.g [0][lA] = nC;  *(h8v*)&sh.s.g [0][lB] = nD;

    float mrun = -1e30f, lrun = 0.f;
    f4v o[4];
    const f4v zf = {0.f, 0.f, 0.f, 0.f};
    #pragma unroll
    for (int tt = 0; tt < 4; tt++) o[tt] = zf;

    f16* const pw = &plds[w][0];

    for (int kb = 0; kb < 64; kb++){
        const int pb = kb & 1;
        __syncthreads();
        if (kb < 63){
            pphi0 += (size_t)64 * CB;  pphi1 += (size_t)64 * CB;
            pg0 += 64;                 pg1 += 64;
            nA = *(const h8v*)pphi0;   nB = *(const h8v*)pphi1;
            nC = *(const h8v*)pg0;     nD = *(const h8v*)pg1;
        }

        // ---- S^T = phi(A) * theta(B) ----
        f4v s[4];
        #pragma unroll
        for (int tt = 0; tt < 4; tt++){
            const f16* pr = &sh.s.ph[pb][(tt * 16 + l15) * 72];
            const h8v pb0 = *(const h8v*)(pr + quad * 8);
            const h8v pb1 = *(const h8v*)(pr + 32 + quad * 8);
            f4v sv = zf;
            sv = __builtin_amdgcn_mfma_f32_16x16x32_f16(pb0, a0, sv, 0, 0, 0);
            sv = __builtin_amdgcn_mfma_f32_16x16x32_f16(pb1, a1, sv, 0, 0, 0);
            s[tt] = sv;
        }
        // ---- online softmax (log2 domain; lane owns query l15) ----
        float smax = fmaxf(fmaxf(s[0][0], s[0][1]), fmaxf(s[0][2], s[0][3]));
        #pragma unroll
        for (int tt = 1; tt < 4; tt++)
            smax = fmaxf(smax, fmaxf(fmaxf(s[tt][0], s[tt][1]), fmaxf(s[tt][2], s[tt][3])));
        smax = fmaxf(smax, __shfl_xor(smax, 16));
        smax = fmaxf(smax, __shfl_xor(smax, 32));
        const float mn = fmaxf(mrun, smax);
        const float alpha = __builtin_amdgcn_exp2f(mrun - mn);
        mrun = mn;
        float lsum = 0.f;
        #pragma unroll
        for (int tt = 0; tt < 4; tt++){
            h4v pv;
            #pragma unroll
            for (int r = 0; r < 4; r++){
                float p = __builtin_amdgcn_exp2f(s[tt][r] - mn);
                lsum += p;
                pv[r] = (f16)p;
            }
            *(h4v*)&pw[l15 * 72 + tt * 16 + quad * 4] = pv;
        }
        lrun = lrun * alpha + lsum;
        #pragma unroll
        for (int tt = 0; tt < 4; tt++)
            #pragma unroll
            for (int r = 0; r < 4; r++)
                o[tt][r] *= alpha;

        const h8v pa0 = *(const h8v*)&pw[l15 * 72 + quad * 8];
        const h8v pa1 = *(const h8v*)&pw[l15 * 72 + 32 + quad * 8];

        // ---- O^T += g(A) * P^T(B) ----
        #pragma unroll
        for (int tt = 0; tt < 4; tt++){
            const f16* gr = &sh.s.g[pb][(tt * 16 + l15) * 72];
            const h8v gb0 = *(const h8v*)(gr + quad * 8);
            const h8v gb1 = *(const h8v*)(gr + 32 + quad * 8);
            o[tt] = __builtin_amdgcn_mfma_f32_16x16x32_f16(gb0, pa0, o[tt], 0, 0, 0);
            o[tt] = __builtin_amdgcn_mfma_f32_16x16x32_f16(gb1, pa1, o[tt], 0, 0, 0);
        }

        if (kb < 63){
            const int nb = pb ^ 1;
            *(h8v*)&sh.s.ph[nb][lA] = nA;  *(h8v*)&sh.s.ph[nb][lB] = nB;
            *(h8v*)&sh.s.g [nb][lA] = nC;  *(h8v*)&sh.s.g [nb][lB] = nD;
        }
    }

    lrun += __shfl_xor(lrun, 16);
    lrun += __shfl_xor(lrun, 32);
    const float inv = 1.0f / lrun;

    #pragma unroll
    for (int tt = 0; tt < 4; tt++){
        h4v yv;
        #pragma unroll
        for (int r = 0; r < 4; r++) yv[r] = (f16)(o[tt][r] * inv);
        *(h4v*)&pw[l15 * 72 + tt * 16 + quad * 4] = yv;
    }

    __syncthreads();   // staging region dead -> overlay fO

    // ---- out-GEMM: D[c][q] = wl(A) * y(B); packed wl fragments ----
    const h8v yB0 = *(const h8v*)&pw[l15 * 72 + quad * 8];
    const h8v yB1 = *(const h8v*)&pw[l15 * 72 + 32 + quad * 8];
    #pragma unroll
    for (int cs = 0; cs < 8; cs++){
        const h8v wa0 = *(const h8v*)&wlp[(cs * 2 + 0) * 512 + lane * 8];
        const h8v wa1 = *(const h8v*)&wlp[(cs * 2 + 1) * 512 + lane * 8];
        f4v acc = zf;
        acc = __builtin_amdgcn_mfma_f32_16x16x32_f16(wa0, yB0, acc, 0, 0, 0);
        acc = __builtin_amdgcn_mfma_f32_16x16x32_f16(wa1, yB1, acc, 0, 0, 0);
        #pragma unroll
        for (int r = 0; r < 4; r++)
            sh.fO[cs * 16 + quad * 4 + r][w * 16 + l15] = acc[r];
    }
    __syncthreads();

    // ---- residual RMW: fully coalesced float4 ----
    #pragma unroll
    for (int i = 0; i < 8; i++){
        const int row = i * 16 + (t >> 4);
        const int nf  = (t & 15) * 4;
        const f4v v = *(const f4v*)&sh.fO[row][nf];
        const size_t idx = ((size_t)(b * CC + row)) * NN + q0 + nf;
        const f4v xv = *(const f4v*)&x[idx];
        f4v ov;
        #pragma unroll
        for (int r = 0; r < 4; r++) ov[r] = v[r] + xv[r];
        *(f4v*)&out[idx] = ov;
    }
}

extern "C" void kernel_launch(void* const* d_in, const int* in_sizes, int n_in,
                              void* d_out, int out_size, void* d_ws, size_t ws_size,
                              hipStream_t stream)
{
    const float* x   = (const float*)d_in[0];
    const float* wth = (const float*)d_in[1];
    const float* wph = (const float*)d_in[2];
    const float* wg  = (const float*)d_in[3];
    const float* wl  = (const float*)d_in[4];
    float* out = (float*)d_out;

    f16* thetaT = (f16*)d_ws;
    f16* phiT   = thetaT + (size_t)NB * NN * CB;
    f16* gbuf   = phiT   + (size_t)NB * NN * CB;
    f16* wthp   = gbuf   + (size_t)NB * NN * CB;
    f16* wphp   = wthp + 8192;
    f16* wgp    = wphp + 8192;
    f16* wlp    = wgp  + 8192;

    pack_w<<<8, 256, 0, stream>>>(wth, wph, wg, wl, wthp, wphp, wgp, wlp);
    proj_kernel<<<NB * 64, 256, 0, stream>>>(x, wthp, wphp, wgp, thetaT, phiT, gbuf);
    attn_kernel<<<NB * 64, 256, 0, stream>>>(thetaT, phiT, gbuf, wlp, x, out);
}